// Round 1
// baseline (2854.424 us; speedup 1.0000x reference)
//
#include <hip/hip_runtime.h>
#include <math.h>

#define WH 64
#define WIN 256
#define TT 4
#define ALPHA_C 0.1f
#define RTILE 4096
#define RVPT 16
#define STATS_GRID 512
#define LOSS_GRID 1024

// ---------- helpers ----------
__device__ __forceinline__ unsigned f2k(float x) {
  unsigned u = __float_as_uint(x);
  return (u & 0x80000000u) ? ~u : (u | 0x80000000u);
}
__device__ __forceinline__ float k2f(unsigned k) {
  unsigned u = (k & 0x80000000u) ? (k ^ 0x80000000u) : ~k;
  return __uint_as_float(u);
}

// ---------- encode: H = l2norm_rows(X @ W + b) ----------
// wave per node: lane j computes H[n][j]; X row staged in LDS via float4.
__global__ __launch_bounds__(256) void k_encode(const float* __restrict__ X,
                                                const float* __restrict__ W,
                                                const float* __restrict__ bias,
                                                float* __restrict__ H, int N) {
  __shared__ __align__(16) float xrow[4][WIN];
  int wv = threadIdx.x >> 6, lane = threadIdx.x & 63;
  int n = blockIdx.x * 4 + wv;
  bool act = n < N;
  if (act) {
    float4 xv = *(const float4*)(X + (size_t)n * WIN + lane * 4);
    *(float4*)&xrow[wv][lane * 4] = xv;
  }
  __syncthreads();
  if (act) {
    float acc = bias[lane];
#pragma unroll 8
    for (int k = 0; k < WIN; ++k) acc = fmaf(xrow[wv][k], W[k * WH + lane], acc);
    float s = acc * acc;
#pragma unroll
    for (int off = 32; off > 0; off >>= 1) s += __shfl_xor(s, off, 64);
    float r = 1.0f / fmaxf(sqrtf(s), 1e-12f);
    H[(size_t)n * WH + lane] = acc * r;
  }
}

// ---------- per-type stats: per-block partials (deterministic reduce) ----------
__global__ __launch_bounds__(256) void k_stats_sum(const float* __restrict__ H,
                                                   const int* __restrict__ nt,
                                                   float* __restrict__ partial,
                                                   float* __restrict__ pcnt, int NW) {
  __shared__ float ls[TT * WH];
  __shared__ float lc[TT];
  ls[threadIdx.x] = 0.0f;
  if (threadIdx.x < TT) lc[threadIdx.x] = 0.0f;
  __syncthreads();
  for (int i = blockIdx.x * 256 + threadIdx.x; i < NW; i += STATS_GRID * 256) {
    int nn = i >> 6, d = i & 63;
    int t = nt[nn];
    atomicAdd(&ls[t * WH + d], H[i]);
    if (d == 0) atomicAdd(&lc[t], 1.0f);
  }
  __syncthreads();
  partial[blockIdx.x * 256 + threadIdx.x] = ls[threadIdx.x];
  if (threadIdx.x < TT) pcnt[blockIdx.x * TT + threadIdx.x] = lc[threadIdx.x];
}

__global__ __launch_bounds__(256) void k_reduce_mean(const float* __restrict__ partial,
                                                     const float* __restrict__ pcnt,
                                                     float* __restrict__ mean,
                                                     float* __restrict__ counts) {
  __shared__ float c[TT];
  if (threadIdx.x < TT) {
    float s = 0.0f;
    for (int b = 0; b < STATS_GRID; ++b) s += pcnt[b * TT + threadIdx.x];
    counts[threadIdx.x] = s;
    c[threadIdx.x] = s;
  }
  __syncthreads();
  float s = 0.0f;
  for (int b = 0; b < STATS_GRID; ++b) s += partial[b * 256 + threadIdx.x];
  mean[threadIdx.x] = s / c[threadIdx.x >> 6];
}

__global__ __launch_bounds__(256) void k_stats_dev(const float* __restrict__ H,
                                                   const int* __restrict__ nt,
                                                   const float* __restrict__ mean,
                                                   float* __restrict__ partial, int NW) {
  __shared__ float ls[TT * WH];
  ls[threadIdx.x] = 0.0f;
  __syncthreads();
  for (int i = blockIdx.x * 256 + threadIdx.x; i < NW; i += STATS_GRID * 256) {
    int nn = i >> 6, d = i & 63;
    int t = nt[nn];
    float v = H[i] - mean[t * WH + d];
    atomicAdd(&ls[t * WH + d], v * v);
  }
  __syncthreads();
  partial[blockIdx.x * 256 + threadIdx.x] = ls[threadIdx.x];
}

__global__ __launch_bounds__(256) void k_reduce_std(const float* __restrict__ partial,
                                                    const float* __restrict__ counts,
                                                    float* __restrict__ stdv) {
  float s = 0.0f;
  for (int b = 0; b < STATS_GRID; ++b) s += partial[b * 256 + threadIdx.x];
  stdv[threadIdx.x] = s / sqrtf(counts[threadIdx.x >> 6] - 1.0f);
}

// tilde = (H - mean)/std, in place; also emit sort keys of tilde
__global__ __launch_bounds__(256) void k_tilde(float* __restrict__ H, const int* __restrict__ nt,
                                               const float* __restrict__ mean,
                                               const float* __restrict__ stdv,
                                               unsigned* __restrict__ ekeys, int NW) {
  int i = blockIdx.x * 256 + threadIdx.x;
  if (i >= NW) return;
  int nn = i >> 6, d = i & 63;
  int t = nt[nn];
  float v = (H[i] - mean[t * WH + d]) / stdv[t * WH + d];
  H[i] = v;
  ekeys[i] = f2k(v);
}

__global__ __launch_bounds__(256) void k_f2k(const float* __restrict__ g,
                                             unsigned* __restrict__ keys, int M) {
  int i = blockIdx.x * 256 + threadIdx.x;
  if (i < M) keys[i] = f2k(g[i]);
}

// ---------- radix sort (4-bit LSD, stable) ----------
__global__ __launch_bounds__(256) void k_radix_hist(const unsigned* __restrict__ in,
                                                    unsigned* __restrict__ hist, int n,
                                                    int shift, int B) {
  __shared__ unsigned h[16];
  if (threadIdx.x < 16) h[threadIdx.x] = 0;
  __syncthreads();
  int base = blockIdx.x * RTILE;
  for (int it = 0; it < RVPT; ++it) {
    int idx = base + it * 256 + threadIdx.x;
    if (idx < n) atomicAdd(&h[(in[idx] >> shift) & 15u], 1u);
  }
  __syncthreads();
  if (threadIdx.x < 16) hist[threadIdx.x * B + blockIdx.x] = h[threadIdx.x];
}

// in-place exclusive scan over a[0..L) — one block of 1024 threads
__global__ __launch_bounds__(1024) void k_scan(unsigned* __restrict__ a, int L) {
  __shared__ unsigned ts[1024];
  int C = (L + 1023) / 1024;
  int lo = threadIdx.x * C, hi = min(lo + C, L);
  unsigned s = 0;
  for (int i = lo; i < hi; ++i) s += a[i];
  ts[threadIdx.x] = s;
  __syncthreads();
  for (int st = 1; st < 1024; st <<= 1) {
    unsigned v = (threadIdx.x >= (unsigned)st) ? ts[threadIdx.x - st] : 0u;
    __syncthreads();
    ts[threadIdx.x] += v;
    __syncthreads();
  }
  unsigned run = (threadIdx.x == 0) ? 0u : ts[threadIdx.x - 1];
  for (int i = lo; i < hi; ++i) {
    unsigned c = a[i];
    a[i] = run;
    run += c;
  }
}

__global__ __launch_bounds__(256) void k_radix_scatter(const unsigned* __restrict__ in,
                                                       unsigned* __restrict__ out,
                                                       const unsigned* __restrict__ hist,
                                                       int n, int shift, int B) {
  __shared__ unsigned base[16];
  __shared__ unsigned runCnt[16];
  __shared__ unsigned waveCnt[4][16];
  int tid = threadIdx.x;
  if (tid < 16) {
    base[tid] = hist[tid * B + blockIdx.x];
    runCnt[tid] = 0;
  }
  int w = tid >> 6, lane = tid & 63;
  unsigned long long laneLt = (1ULL << lane) - 1ULL;
  int blockBase = blockIdx.x * RTILE;
  for (int it = 0; it < RVPT; ++it) {
    int idx = blockBase + it * 256 + tid;
    bool valid = idx < n;
    unsigned key = valid ? in[idx] : 0u;
    unsigned dig = (key >> shift) & 15u;
    unsigned long long vm = __ballot(valid);
    unsigned long long m = vm;
#pragma unroll
    for (int b = 0; b < 4; ++b) {
      unsigned long long bb = __ballot((dig >> b) & 1u);
      m &= ((dig >> b) & 1u) ? bb : ~bb;
    }
    unsigned lr = (unsigned)__popcll(m & laneLt);
    unsigned cnt = (unsigned)__popcll(m);
    if (tid < 64) waveCnt[tid >> 4][tid & 15] = 0;
    __syncthreads();
    if (valid && lr == 0) waveCnt[w][dig] = cnt;
    __syncthreads();
    if (valid) {
      unsigned before = runCnt[dig];
      for (int ww = 0; ww < w; ++ww) before += waveCnt[ww][dig];
      out[base[dig] + before + lr] = key;
    }
    __syncthreads();
    if (tid < 16)
      runCnt[tid] += waveCnt[0][tid] + waveCnt[1][tid] + waveCnt[2][tid] + waveCnt[3][tid];
    __syncthreads();
  }
}

// ---------- wasserstein loss ----------
__global__ __launch_bounds__(256) void k_loss(const unsigned* __restrict__ ga,
                                              const unsigned* __restrict__ ea,
                                              double* __restrict__ pl, int M) {
  double s = 0.0;
  for (int i = blockIdx.x * 256 + threadIdx.x; i < M; i += LOSS_GRID * 256)
    s += (double)fabsf(k2f(ga[i]) - k2f(ea[i]));
  __shared__ double sd[256];
  sd[threadIdx.x] = s;
  __syncthreads();
  for (int st = 128; st > 0; st >>= 1) {
    if (threadIdx.x < st) sd[threadIdx.x] += sd[threadIdx.x + st];
    __syncthreads();
  }
  if (threadIdx.x == 0) pl[blockIdx.x] = sd[0];
}

__global__ void k_loss_fin(const double* __restrict__ pl, float* __restrict__ out, int M, int NW) {
  double s = 0.0;
  for (int b = 0; b < LOSS_GRID; ++b) s += pl[b];
  out[NW] = (float)(s / (double)M);
}

// ---------- CSR build (counting sort of edges by dst) ----------
__global__ __launch_bounds__(256) void k_degi(const int* __restrict__ dst,
                                              unsigned* __restrict__ degi, int E) {
  int e = blockIdx.x * 256 + threadIdx.x;
  if (e < E) atomicAdd(&degi[dst[e]], 1u);
}
__global__ __launch_bounds__(256) void k_copy_u32(const unsigned* __restrict__ a,
                                                  unsigned* __restrict__ b, int n) {
  int i = blockIdx.x * 256 + threadIdx.x;
  if (i < n) b[i] = a[i];
}
__global__ __launch_bounds__(256) void k_build(const int* __restrict__ src,
                                               const int* __restrict__ dst,
                                               const unsigned* __restrict__ off,
                                               unsigned* __restrict__ cur,
                                               unsigned* __restrict__ esrc, int E) {
  int e = blockIdx.x * 256 + threadIdx.x;
  if (e >= E) return;
  int t = dst[e];
  unsigned p = off[t] + atomicAdd(&cur[t], 1u);
  esrc[p] = (unsigned)src[e];
}

// ---------- diffusion hop: Zn = 0.9/deg * sum_{src in CSR(n)} Z[src] + 0.1*tilde ----------
__global__ __launch_bounds__(256) void k_spmm_csr(const unsigned* __restrict__ off,
                                                  const unsigned* __restrict__ degi,
                                                  const unsigned* __restrict__ esrc,
                                                  const float* __restrict__ Z,
                                                  const float* __restrict__ tilde,
                                                  float* __restrict__ Zn, int N) {
  int wv = threadIdx.x >> 6, lane = threadIdx.x & 63;
  int n = blockIdx.x * 4 + wv;
  if (n >= N) return;
  unsigned st = off[n], dg = degi[n];
  unsigned end = st + dg;
  float acc = 0.0f;
  for (unsigned base = st; base < end; base += 64) {
    unsigned idx = base + lane;
    unsigned sv = (idx < end) ? esrc[idx] : 0u;
    int cnt = (int)min(64u, end - base);
    for (int t = 0; t < cnt; ++t) {
      unsigned s = __shfl(sv, t, 64);
      acc += Z[(size_t)s * WH + lane];
    }
  }
  float wn = (1.0f - ALPHA_C) / fmaxf((float)dg, 1.0f);
  Zn[(size_t)n * WH + lane] = wn * acc + ALPHA_C * tilde[(size_t)n * WH + lane];
}

// ---------- epilogue: denorm + row-L2 ----------
__global__ __launch_bounds__(256) void k_final(const float* __restrict__ Z,
                                               const int* __restrict__ nt,
                                               const float* __restrict__ mean,
                                               const float* __restrict__ stdv,
                                               float* __restrict__ out, int N) {
  int wv = threadIdx.x >> 6, lane = threadIdx.x & 63;
  int n = blockIdx.x * 4 + wv;
  if (n >= N) return;
  int t = nt[n];
  float z = Z[(size_t)n * WH + lane] * stdv[t * WH + lane] + mean[t * WH + lane];
  float s = z * z;
#pragma unroll
  for (int off = 32; off > 0; off >>= 1) s += __shfl_xor(s, off, 64);
  float r = 1.0f / fmaxf(sqrtf(s), 1e-12f);
  out[(size_t)n * WH + lane] = z * r;
}

extern "C" void kernel_launch(void* const* d_in, const int* in_sizes, int n_in,
                              void* d_out, int out_size, void* d_ws, size_t ws_size,
                              hipStream_t stream) {
  const float* X = (const float*)d_in[0];
  const float* W = (const float*)d_in[1];
  const float* bias = (const float*)d_in[2];
  const float* g = (const float*)d_in[3];
  const int* ei = (const int*)d_in[4];
  const int* nt = (const int*)d_in[5];

  const int N = in_sizes[5];
  const int E = in_sizes[4] / 2;
  const int M = in_sizes[3];   // N * WH
  const int NW = N * WH;
  const int* srcp = ei;
  const int* dstp = ei + E;

  char* w = (char*)d_ws;
  size_t o = 0;
  auto alloc = [&](size_t bytes) {
    size_t r = o;
    o += (bytes + 255) & ~(size_t)255;
    return r;
  };
  const int B = (M + RTILE - 1) / RTILE;
  size_t off_stats   = alloc(4096);                       // counts@0, mean@256, std@1280
  size_t off_partial = alloc((size_t)STATS_GRID * 256 * 4);
  size_t off_pcnt    = alloc((size_t)STATS_GRID * TT * 4);
  size_t off_ploss   = alloc((size_t)LOSS_GRID * 8);
  size_t off_degi    = alloc((size_t)N * 4);              // memset region start
  size_t off_cur     = alloc((size_t)N * 4);              // memset region end
  size_t off_off     = alloc((size_t)N * 4);
  size_t off_esrc    = alloc((size_t)E * 4);
  size_t off_hist    = alloc((size_t)16 * B * 4);
  size_t off_tilde   = alloc((size_t)NW * 4);
  size_t off_gk      = alloc((size_t)NW * 4);
  size_t off_ek      = alloc((size_t)NW * 4);
  size_t off_tmp     = alloc((size_t)NW * 4);

  float* counts = (float*)(w + off_stats + 0);
  float* mean   = (float*)(w + off_stats + 256);
  float* stdv   = (float*)(w + off_stats + 1280);
  float* partial = (float*)(w + off_partial);
  float* pcnt    = (float*)(w + off_pcnt);
  double* ploss  = (double*)(w + off_ploss);
  unsigned* degi = (unsigned*)(w + off_degi);
  unsigned* cur  = (unsigned*)(w + off_cur);
  unsigned* offp = (unsigned*)(w + off_off);
  unsigned* esrc = (unsigned*)(w + off_esrc);
  unsigned* hist = (unsigned*)(w + off_hist);
  float* tilde   = (float*)(w + off_tilde);
  unsigned* gk   = (unsigned*)(w + off_gk);
  unsigned* ek   = (unsigned*)(w + off_ek);
  unsigned* tk   = (unsigned*)(w + off_tmp);
  float* out = (float*)d_out;

  // zero degree + cursor arrays (adjacent region)
  hipMemsetAsync(w + off_degi, 0, off_cur - off_degi + (size_t)N * 4, stream);

  // 1) encode + L2 norm -> tilde buffer (holds H for now)
  k_encode<<<(N + 3) / 4, 256, 0, stream>>>(X, W, bias, tilde, N);

  // 2) per-type stats
  k_stats_sum<<<STATS_GRID, 256, 0, stream>>>(tilde, nt, partial, pcnt, NW);
  k_reduce_mean<<<1, 256, 0, stream>>>(partial, pcnt, mean, counts);
  k_stats_dev<<<STATS_GRID, 256, 0, stream>>>(tilde, nt, mean, partial, NW);
  k_reduce_std<<<1, 256, 0, stream>>>(partial, counts, stdv);

  // 3) tilde (in place) + sort keys
  k_tilde<<<(NW + 255) / 256, 256, 0, stream>>>(tilde, nt, mean, stdv, ek, NW);
  k_f2k<<<(M + 255) / 256, 256, 0, stream>>>(g, gk, M);

  // 4) radix sort both key arrays (8 passes x 4 bits, ping-pong with tk)
  for (int arr = 0; arr < 2; ++arr) {
    unsigned* a = (arr == 0) ? gk : ek;
    for (int p = 0; p < 8; ++p) {
      unsigned* src_ = (p & 1) ? tk : a;
      unsigned* dst_ = (p & 1) ? a : tk;
      k_radix_hist<<<B, 256, 0, stream>>>(src_, hist, M, p * 4, B);
      k_scan<<<1, 1024, 0, stream>>>(hist, 16 * B);
      k_radix_scatter<<<B, 256, 0, stream>>>(src_, dst_, hist, M, p * 4, B);
    }
  }

  // 5) loss = mean |sorted(g) - sorted(emb)|
  k_loss<<<LOSS_GRID, 256, 0, stream>>>(gk, ek, ploss, M);
  k_loss_fin<<<1, 1, 0, stream>>>(ploss, out, M, NW);

  // 6) CSR build (edges grouped by dst)
  k_degi<<<(E + 255) / 256, 256, 0, stream>>>(dstp, degi, E);
  k_copy_u32<<<(N + 255) / 256, 256, 0, stream>>>(degi, offp, N);
  k_scan<<<1, 1024, 0, stream>>>(offp, N);
  k_build<<<(E + 255) / 256, 256, 0, stream>>>(srcp, dstp, offp, cur, esrc, E);

  // 7) K=10 diffusion hops, ping-pong reusing sort buffers (gk/ek regions free now)
  float* bufA = (float*)(w + off_gk);
  float* bufB = (float*)(w + off_ek);
  const float* Zc = tilde;
  for (int k = 0; k < 10; ++k) {
    float* Zn = (k & 1) ? bufB : bufA;
    k_spmm_csr<<<(N + 3) / 4, 256, 0, stream>>>(offp, degi, esrc, Zc, tilde, Zn, N);
    Zc = Zn;
  }

  // 8) denorm + row L2 -> out
  k_final<<<(N + 3) / 4, 256, 0, stream>>>(Zc, nt, mean, stdv, out, N);
}

// Round 3
// 1922.398 us; speedup vs baseline: 1.4848x; 1.4848x over previous
//
#include <hip/hip_runtime.h>
#include <math.h>

#define WH 64
#define WIN 256
#define TT 4
#define ALPHA_C 0.1f
#define STATS_GRID 256
#define BN 64
#define KC 64
#define XS_STRIDE (KC + 4)
#define BINS (1 << 22)          // 4194304 bins over [-32, 32)
#define BIN_SCALE 65536.0f      // BINS / 64
#define WCHUNK 4096             // bins per block in wasserstein passes
#define WGRID (BINS / WCHUNK)   // 1024

// ---------- encode: H = l2norm_rows(X @ W + b), tiled fp32 ----------
// block: 256 threads -> 64 nodes x 64 cols; thread: 4 nodes x 4 cols.
__global__ __launch_bounds__(256) void k_encode(const float* __restrict__ X,
                                                const float* __restrict__ W,
                                                const float* __restrict__ bias,
                                                float* __restrict__ H, int N) {
  __shared__ __align__(16) float Xs[BN * XS_STRIDE];
  __shared__ __align__(16) float Ws[KC * WH];
  int tid = threadIdx.x;
  int tn = tid >> 4, tc = tid & 15;
  int nodeBase = blockIdx.x * BN;
  float acc[4][4] = {};
  for (int k0 = 0; k0 < WIN; k0 += KC) {
    __syncthreads();
    // stage W chunk (row-major, contiguous copy)
    const float4* Wg4 = (const float4*)(W + (size_t)k0 * WH);
    float4* Ws4 = (float4*)Ws;
#pragma unroll
    for (int i = 0; i < 4; ++i) Ws4[tid + i * 256] = Wg4[tid + i * 256];
    // stage X chunk [node][kk], padded stride
#pragma unroll
    for (int p = 0; p < 4; ++p) {
      int ln = p * 16 + tn;
      int node = nodeBase + ln;
      if (node < N) {
        float4 xv = *(const float4*)(X + (size_t)node * WIN + k0 + tc * 4);
        *(float4*)&Xs[ln * XS_STRIDE + tc * 4] = xv;
      }
    }
    __syncthreads();
    for (int kk = 0; kk < KC; kk += 4) {
      float4 b0 = *(const float4*)&Ws[(kk + 0) * WH + tc * 4];
      float4 b1 = *(const float4*)&Ws[(kk + 1) * WH + tc * 4];
      float4 b2 = *(const float4*)&Ws[(kk + 2) * WH + tc * 4];
      float4 b3 = *(const float4*)&Ws[(kk + 3) * WH + tc * 4];
#pragma unroll
      for (int i = 0; i < 4; ++i) {
        float4 a = *(const float4*)&Xs[(tn * 4 + i) * XS_STRIDE + kk];
        acc[i][0] += a.x * b0.x + a.y * b1.x + a.z * b2.x + a.w * b3.x;
        acc[i][1] += a.x * b0.y + a.y * b1.y + a.z * b2.y + a.w * b3.y;
        acc[i][2] += a.x * b0.z + a.y * b1.z + a.z * b2.z + a.w * b3.z;
        acc[i][3] += a.x * b0.w + a.y * b1.w + a.z * b2.w + a.w * b3.w;
      }
    }
  }
  float4 bv = *(const float4*)(bias + tc * 4);
#pragma unroll
  for (int i = 0; i < 4; ++i) {
    float h0 = acc[i][0] + bv.x, h1 = acc[i][1] + bv.y;
    float h2 = acc[i][2] + bv.z, h3 = acc[i][3] + bv.w;
    float s = h0 * h0 + h1 * h1 + h2 * h2 + h3 * h3;
    s += __shfl_xor(s, 1, 64);
    s += __shfl_xor(s, 2, 64);
    s += __shfl_xor(s, 4, 64);
    s += __shfl_xor(s, 8, 64);
    float r = 1.0f / fmaxf(sqrtf(s), 1e-12f);
    int node = nodeBase + tn * 4 + i;
    if (node < N) {
      float4 o = {h0 * r, h1 * r, h2 * r, h3 * r};
      *(float4*)(H + (size_t)node * WH + tc * 4) = o;
    }
  }
}

// ---------- per-type stats: fused sum + sumsq + counts ----------
__global__ __launch_bounds__(256) void k_stats(const float* __restrict__ H,
                                               const int* __restrict__ nt,
                                               float* __restrict__ psum,
                                               float* __restrict__ psq,
                                               float* __restrict__ pcnt, int NW) {
  __shared__ float ls[TT * WH], ls2[TT * WH];
  __shared__ float lc[TT];
  ls[threadIdx.x] = 0.0f;
  ls2[threadIdx.x] = 0.0f;
  if (threadIdx.x < TT) lc[threadIdx.x] = 0.0f;
  __syncthreads();
  for (int i = blockIdx.x * 256 + threadIdx.x; i < NW; i += STATS_GRID * 256) {
    int nn = i >> 6, d = i & 63;
    int t = nt[nn];
    float v = H[i];
    atomicAdd(&ls[t * WH + d], v);
    atomicAdd(&ls2[t * WH + d], v * v);
    if (d == 0) atomicAdd(&lc[t], 1.0f);
  }
  __syncthreads();
  psum[blockIdx.x * 256 + threadIdx.x] = ls[threadIdx.x];
  psq[blockIdx.x * 256 + threadIdx.x] = ls2[threadIdx.x];
  if (threadIdx.x < TT) pcnt[blockIdx.x * TT + threadIdx.x] = lc[threadIdx.x];
}

__global__ __launch_bounds__(256) void k_reduce_stats(const float* __restrict__ psum,
                                                      const float* __restrict__ psq,
                                                      const float* __restrict__ pcnt,
                                                      float* __restrict__ mean,
                                                      float* __restrict__ stdv,
                                                      float* __restrict__ counts) {
  __shared__ float c[TT];
  if (threadIdx.x < TT) {
    float s = 0.0f;
    for (int b = 0; b < STATS_GRID; ++b) s += pcnt[b * TT + threadIdx.x];
    counts[threadIdx.x] = s;
    c[threadIdx.x] = s;
  }
  __syncthreads();
  float s = 0.0f, q = 0.0f;
  for (int b = 0; b < STATS_GRID; ++b) {
    s += psum[b * 256 + threadIdx.x];
    q += psq[b * 256 + threadIdx.x];
  }
  float n = c[threadIdx.x >> 6];
  float m = s / n;
  mean[threadIdx.x] = m;
  stdv[threadIdx.x] = (q - s * s / n) / sqrtf(n - 1.0f);
}

// tilde = (H - mean)/std in place; fused histogram of emb
__global__ __launch_bounds__(256) void k_tilde(float* __restrict__ H, const int* __restrict__ nt,
                                               const float* __restrict__ mean,
                                               const float* __restrict__ stdv,
                                               unsigned* __restrict__ binsE, int NW) {
  int i = blockIdx.x * 256 + threadIdx.x;
  if (i >= NW) return;
  int nn = i >> 6, d = i & 63;
  int t = nt[nn];
  float v = (H[i] - mean[t * WH + d]) / stdv[t * WH + d];
  H[i] = v;
  int b = (int)((v + 32.0f) * BIN_SCALE);
  b = min(max(b, 0), BINS - 1);
  atomicAdd(&binsE[b], 1u);
}

__global__ __launch_bounds__(256) void k_histG(const float* __restrict__ g,
                                               unsigned* __restrict__ binsG, int M) {
  int i = blockIdx.x * 256 + threadIdx.x;
  if (i >= M) return;
  float v = g[i];
  int b = (int)((v + 32.0f) * BIN_SCALE);
  b = min(max(b, 0), BINS - 1);
  atomicAdd(&binsG[b], 1u);
}

// ---------- wasserstein via CDF-difference integral ----------
// pass 1: per-block sum of d[b] = cg[b]-ce[b]
__global__ __launch_bounds__(256) void k_wpart(const unsigned* __restrict__ cg,
                                               const unsigned* __restrict__ ce,
                                               unsigned* __restrict__ wpart) {
  int base = blockIdx.x * WCHUNK + threadIdx.x * 16;
  int s = 0;
  for (int i = 0; i < 16; ++i) s += (int)cg[base + i] - (int)ce[base + i];
  __shared__ int sd[256];
  sd[threadIdx.x] = s;
  __syncthreads();
  for (int st = 128; st > 0; st >>= 1) {
    if (threadIdx.x < st) sd[threadIdx.x] += sd[threadIdx.x + st];
    __syncthreads();
  }
  if (threadIdx.x == 0) wpart[blockIdx.x] = (unsigned)sd[0];
}

// in-place exclusive scan over a[0..L) — one block of 1024 threads (unsigned wrap == int)
__global__ __launch_bounds__(1024) void k_scan(unsigned* __restrict__ a, int L) {
  __shared__ unsigned ts[1024];
  int C = (L + 1023) / 1024;
  int lo = threadIdx.x * C, hi = min(lo + C, L);
  unsigned s = 0;
  for (int i = lo; i < hi; ++i) s += a[i];
  ts[threadIdx.x] = s;
  __syncthreads();
  for (int st = 1; st < 1024; st <<= 1) {
    unsigned v = (threadIdx.x >= (unsigned)st) ? ts[threadIdx.x - st] : 0u;
    __syncthreads();
    ts[threadIdx.x] += v;
    __syncthreads();
  }
  unsigned run = (threadIdx.x == 0) ? 0u : ts[threadIdx.x - 1];
  for (int i = lo; i < hi; ++i) {
    unsigned c = a[i];
    a[i] = run;
    run += c;
  }
}

// pass 2: with global block offsets, accumulate sum |prefix| per block
__global__ __launch_bounds__(256) void k_wsum(const unsigned* __restrict__ cg,
                                              const unsigned* __restrict__ ce,
                                              const unsigned* __restrict__ wpartScanned,
                                              long long* __restrict__ wsabs) {
  int base = blockIdx.x * WCHUNK + threadIdx.x * 16;
  int d[16];
  int s = 0;
  for (int i = 0; i < 16; ++i) {
    d[i] = (int)cg[base + i] - (int)ce[base + i];
    s += d[i];
  }
  __shared__ int sc[256];
  sc[threadIdx.x] = s;
  __syncthreads();
  for (int st = 1; st < 256; st <<= 1) {
    int v = (threadIdx.x >= (unsigned)st) ? sc[threadIdx.x - st] : 0;
    __syncthreads();
    sc[threadIdx.x] += v;
    __syncthreads();
  }
  int run = (int)wpartScanned[blockIdx.x] + sc[threadIdx.x] - s;  // exclusive prefix
  long long a = 0;
  for (int i = 0; i < 16; ++i) {
    run += d[i];
    a += (long long)(run < 0 ? -run : run);
  }
  __shared__ long long rd[256];
  rd[threadIdx.x] = a;
  __syncthreads();
  for (int st = 128; st > 0; st >>= 1) {
    if (threadIdx.x < st) rd[threadIdx.x] += rd[threadIdx.x + st];
    __syncthreads();
  }
  if (threadIdx.x == 0) wsabs[blockIdx.x] = rd[0];
}

__global__ void k_loss_fin(const long long* __restrict__ wsabs, float* __restrict__ out,
                           int M, int NW) {
  long long tot = 0;
  for (int b = 0; b < WGRID; ++b) tot += wsabs[b];
  out[NW] = (float)((double)tot * (64.0 / (double)BINS) / (double)M);
}

// ---------- CSR build (counting sort of edges by dst) ----------
__global__ __launch_bounds__(256) void k_degi(const int* __restrict__ dst,
                                              unsigned* __restrict__ degi, int E) {
  int e = blockIdx.x * 256 + threadIdx.x;
  if (e < E) atomicAdd(&degi[dst[e]], 1u);
}
__global__ __launch_bounds__(256) void k_copy_u32(const unsigned* __restrict__ a,
                                                  unsigned* __restrict__ b, int n) {
  int i = blockIdx.x * 256 + threadIdx.x;
  if (i < n) b[i] = a[i];
}
__global__ __launch_bounds__(256) void k_build(const int* __restrict__ src,
                                               const int* __restrict__ dst,
                                               const unsigned* __restrict__ off,
                                               unsigned* __restrict__ cur,
                                               unsigned* __restrict__ esrc, int E) {
  int e = blockIdx.x * 256 + threadIdx.x;
  if (e >= E) return;
  int t = dst[e];
  unsigned p = off[t] + atomicAdd(&cur[t], 1u);
  esrc[p] = (unsigned)src[e];
}

// ---------- diffusion hop ----------
// wave per node; lane = g*16+c: g = edge slot (4 independent gather chains), c = col quarter
__global__ __launch_bounds__(256) void k_spmm(const unsigned* __restrict__ off,
                                              const unsigned* __restrict__ degi,
                                              const unsigned* __restrict__ esrc,
                                              const float* __restrict__ Z,
                                              const float* __restrict__ tilde,
                                              float* __restrict__ Zn, int N) {
  int wv = threadIdx.x >> 6, lane = threadIdx.x & 63;
  int n = blockIdx.x * 4 + wv;
  if (n >= N) return;
  int g = lane >> 4, c = lane & 15;
  unsigned st = off[n], dg = degi[n];
  float4 acc = {0.f, 0.f, 0.f, 0.f};
  for (unsigned e = g; e < dg; e += 4) {
    unsigned s = esrc[st + e];
    float4 v = *((const float4*)(Z + (size_t)s * WH) + c);
    acc.x += v.x;
    acc.y += v.y;
    acc.z += v.z;
    acc.w += v.w;
  }
#pragma unroll
  for (int m = 16; m <= 32; m <<= 1) {
    acc.x += __shfl_xor(acc.x, m, 64);
    acc.y += __shfl_xor(acc.y, m, 64);
    acc.z += __shfl_xor(acc.z, m, 64);
    acc.w += __shfl_xor(acc.w, m, 64);
  }
  if (g == 0) {
    float wn = (1.0f - ALPHA_C) / fmaxf((float)dg, 1.0f);
    float4 t = *((const float4*)(tilde + (size_t)n * WH) + c);
    float4 o = {wn * acc.x + ALPHA_C * t.x, wn * acc.y + ALPHA_C * t.y,
                wn * acc.z + ALPHA_C * t.z, wn * acc.w + ALPHA_C * t.w};
    *((float4*)(Zn + (size_t)n * WH) + c) = o;
  }
}

// ---------- epilogue: denorm + row-L2 ----------
__global__ __launch_bounds__(256) void k_final(const float* __restrict__ Z,
                                               const int* __restrict__ nt,
                                               const float* __restrict__ mean,
                                               const float* __restrict__ stdv,
                                               float* __restrict__ out, int N) {
  int wv = threadIdx.x >> 6, lane = threadIdx.x & 63;
  int n = blockIdx.x * 4 + wv;
  if (n >= N) return;
  int t = nt[n];
  float z = Z[(size_t)n * WH + lane] * stdv[t * WH + lane] + mean[t * WH + lane];
  float s = z * z;
#pragma unroll
  for (int off = 32; off > 0; off >>= 1) s += __shfl_xor(s, off, 64);
  float r = 1.0f / fmaxf(sqrtf(s), 1e-12f);
  out[(size_t)n * WH + lane] = z * r;
}

extern "C" void kernel_launch(void* const* d_in, const int* in_sizes, int n_in,
                              void* d_out, int out_size, void* d_ws, size_t ws_size,
                              hipStream_t stream) {
  const float* X = (const float*)d_in[0];
  const float* W = (const float*)d_in[1];
  const float* bias = (const float*)d_in[2];
  const float* g = (const float*)d_in[3];
  const int* ei = (const int*)d_in[4];
  const int* nt = (const int*)d_in[5];

  const int N = in_sizes[5];
  const int E = in_sizes[4] / 2;
  const int M = in_sizes[3];  // N * WH
  const int NW = N * WH;
  const int* srcp = ei;
  const int* dstp = ei + E;

  char* w = (char*)d_ws;
  size_t o = 0;
  auto alloc = [&](size_t bytes) {
    size_t r = o;
    o += (bytes + 255) & ~(size_t)255;
    return r;
  };
  size_t off_stats = alloc(4096);  // counts@0, mean@256, std@1280
  size_t off_psum  = alloc((size_t)STATS_GRID * 256 * 4);
  size_t off_psq   = alloc((size_t)STATS_GRID * 256 * 4);
  size_t off_pcnt  = alloc((size_t)STATS_GRID * TT * 4);
  size_t off_wpart = alloc((size_t)WGRID * 4);
  size_t off_wsabs = alloc((size_t)WGRID * 8);
  size_t off_degi  = alloc((size_t)N * 4);  // memset region 1 start
  size_t off_cur   = alloc((size_t)N * 4);  // memset region 1 end (NOTE: slot is 256B-aligned)
  size_t off_off   = alloc((size_t)N * 4);
  size_t off_esrc  = alloc((size_t)E * 4);
  size_t off_tilde = alloc((size_t)NW * 4);
  size_t off_bufA  = alloc((size_t)NW * 4);  // bins alias starts here
  size_t off_bufB  = alloc((size_t)NW * 4);

  float* counts = (float*)(w + off_stats + 0);
  float* mean   = (float*)(w + off_stats + 256);
  float* stdv   = (float*)(w + off_stats + 1280);
  float* psum   = (float*)(w + off_psum);
  float* psq    = (float*)(w + off_psq);
  float* pcnt   = (float*)(w + off_pcnt);
  unsigned* wpart = (unsigned*)(w + off_wpart);
  long long* wsabs = (long long*)(w + off_wsabs);
  unsigned* degi = (unsigned*)(w + off_degi);
  unsigned* cur  = (unsigned*)(w + off_cur);
  unsigned* offp = (unsigned*)(w + off_off);
  unsigned* esrc = (unsigned*)(w + off_esrc);
  float* tilde   = (float*)(w + off_tilde);
  float* bufA    = (float*)(w + off_bufA);
  float* bufB    = (float*)(w + off_bufB);
  // bins alias the (not-yet-used) diffusion ping-pong buffers: 33.6 MB < 51.2 MB
  unsigned* binsG = (unsigned*)(w + off_bufA);
  unsigned* binsE = binsG + BINS;
  float* out = (float*)d_out;

  // zero degree+cursor. CRITICAL: span is off_cur - off_degi + N*4 (covers the
  // 128B alignment pad between the slots) — round-2's 2*N*4 left the tail of
  // `cur` poisoned -> wild esrc writes -> GPU fault.
  hipMemsetAsync(w + off_degi, 0, off_cur - off_degi + (size_t)N * 4, stream);
  hipMemsetAsync((void*)binsG, 0, (size_t)2 * BINS * 4, stream);

  // 1) encode + L2 norm -> tilde buffer (holds H for now)
  k_encode<<<(N + BN - 1) / BN, 256, 0, stream>>>(X, W, bias, tilde, N);

  // 2) per-type stats (fused sum/sumsq/count) + reduce
  k_stats<<<STATS_GRID, 256, 0, stream>>>(tilde, nt, psum, psq, pcnt, NW);
  k_reduce_stats<<<1, 256, 0, stream>>>(psum, psq, pcnt, mean, stdv, counts);

  // 3) tilde in place + emb histogram; gaussian histogram
  k_tilde<<<(NW + 255) / 256, 256, 0, stream>>>(tilde, nt, mean, stdv, binsE, NW);
  k_histG<<<(M + 255) / 256, 256, 0, stream>>>(g, binsG, M);

  // 4) W1 = (delta/M) * sum_b |prefix(cg-ce)|
  k_wpart<<<WGRID, 256, 0, stream>>>(binsG, binsE, wpart);
  k_scan<<<1, 1024, 0, stream>>>(wpart, WGRID);
  k_wsum<<<WGRID, 256, 0, stream>>>(binsG, binsE, wpart, wsabs);
  k_loss_fin<<<1, 1, 0, stream>>>(wsabs, out, M, NW);

  // 5) CSR build (edges grouped by dst)
  k_degi<<<(E + 255) / 256, 256, 0, stream>>>(dstp, degi, E);
  k_copy_u32<<<(N + 255) / 256, 256, 0, stream>>>(degi, offp, N);
  k_scan<<<1, 1024, 0, stream>>>(offp, N);
  k_build<<<(E + 255) / 256, 256, 0, stream>>>(srcp, dstp, offp, cur, esrc, E);

  // 6) K=10 diffusion hops, ping-pong (bins are dead now; buffers reusable)
  const float* Zc = tilde;
  for (int k = 0; k < 10; ++k) {
    float* Zn = (k & 1) ? bufB : bufA;
    k_spmm<<<(N + 3) / 4, 256, 0, stream>>>(offp, degi, esrc, Zc, tilde, Zn, N);
    Zc = Zn;
  }

  // 7) denorm + row L2 -> out
  k_final<<<(N + 3) / 4, 256, 0, stream>>>(Zc, nt, mean, stdv, out, N);
}

// Round 4
// 1433.442 us; speedup vs baseline: 1.9913x; 1.3411x over previous
//
#include <hip/hip_runtime.h>
#include <math.h>

#define WH 64
#define WIN 256
#define TT 4
#define ALPHA_C 0.1f
#define STATS_GRID 256
#define BN 64
#define KC 64
#define XS_STRIDE (KC + 4)
#define BINS 16384              // bins over [-8, 8)
#define BIN_SCALE 1024.0f       // BINS / 16
#define HG 256                  // histogram grid (partial hists)

// ---------- encode: H = l2norm_rows(X @ W + b), tiled fp32 ----------
__global__ __launch_bounds__(256) void k_encode(const float* __restrict__ X,
                                                const float* __restrict__ W,
                                                const float* __restrict__ bias,
                                                float* __restrict__ H, int N) {
  __shared__ __align__(16) float Xs[BN * XS_STRIDE];
  __shared__ __align__(16) float Ws[KC * WH];
  int tid = threadIdx.x;
  int tn = tid >> 4, tc = tid & 15;
  int nodeBase = blockIdx.x * BN;
  float acc[4][4] = {};
  for (int k0 = 0; k0 < WIN; k0 += KC) {
    __syncthreads();
    const float4* Wg4 = (const float4*)(W + (size_t)k0 * WH);
    float4* Ws4 = (float4*)Ws;
#pragma unroll
    for (int i = 0; i < 4; ++i) Ws4[tid + i * 256] = Wg4[tid + i * 256];
#pragma unroll
    for (int p = 0; p < 4; ++p) {
      int ln = p * 16 + tn;
      int node = nodeBase + ln;
      if (node < N) {
        float4 xv = *(const float4*)(X + (size_t)node * WIN + k0 + tc * 4);
        *(float4*)&Xs[ln * XS_STRIDE + tc * 4] = xv;
      }
    }
    __syncthreads();
    for (int kk = 0; kk < KC; kk += 4) {
      float4 b0 = *(const float4*)&Ws[(kk + 0) * WH + tc * 4];
      float4 b1 = *(const float4*)&Ws[(kk + 1) * WH + tc * 4];
      float4 b2 = *(const float4*)&Ws[(kk + 2) * WH + tc * 4];
      float4 b3 = *(const float4*)&Ws[(kk + 3) * WH + tc * 4];
#pragma unroll
      for (int i = 0; i < 4; ++i) {
        float4 a = *(const float4*)&Xs[(tn * 4 + i) * XS_STRIDE + kk];
        acc[i][0] += a.x * b0.x + a.y * b1.x + a.z * b2.x + a.w * b3.x;
        acc[i][1] += a.x * b0.y + a.y * b1.y + a.z * b2.y + a.w * b3.y;
        acc[i][2] += a.x * b0.z + a.y * b1.z + a.z * b2.z + a.w * b3.z;
        acc[i][3] += a.x * b0.w + a.y * b1.w + a.z * b2.w + a.w * b3.w;
      }
    }
  }
  float4 bv = *(const float4*)(bias + tc * 4);
#pragma unroll
  for (int i = 0; i < 4; ++i) {
    float h0 = acc[i][0] + bv.x, h1 = acc[i][1] + bv.y;
    float h2 = acc[i][2] + bv.z, h3 = acc[i][3] + bv.w;
    float s = h0 * h0 + h1 * h1 + h2 * h2 + h3 * h3;
    s += __shfl_xor(s, 1, 64);
    s += __shfl_xor(s, 2, 64);
    s += __shfl_xor(s, 4, 64);
    s += __shfl_xor(s, 8, 64);
    float r = 1.0f / fmaxf(sqrtf(s), 1e-12f);
    int node = nodeBase + tn * 4 + i;
    if (node < N) {
      float4 o = {h0 * r, h1 * r, h2 * r, h3 * r};
      *(float4*)(H + (size_t)node * WH + tc * 4) = o;
    }
  }
}

// ---------- per-type stats: fused sum + sumsq + counts ----------
__global__ __launch_bounds__(256) void k_stats(const float* __restrict__ H,
                                               const int* __restrict__ nt,
                                               float* __restrict__ psum,
                                               float* __restrict__ psq,
                                               float* __restrict__ pcnt, int NW) {
  __shared__ float ls[TT * WH], ls2[TT * WH];
  __shared__ float lc[TT];
  ls[threadIdx.x] = 0.0f;
  ls2[threadIdx.x] = 0.0f;
  if (threadIdx.x < TT) lc[threadIdx.x] = 0.0f;
  __syncthreads();
  for (int i = blockIdx.x * 256 + threadIdx.x; i < NW; i += STATS_GRID * 256) {
    int nn = i >> 6, d = i & 63;
    int t = nt[nn];
    float v = H[i];
    atomicAdd(&ls[t * WH + d], v);
    atomicAdd(&ls2[t * WH + d], v * v);
    if (d == 0) atomicAdd(&lc[t], 1.0f);
  }
  __syncthreads();
  psum[blockIdx.x * 256 + threadIdx.x] = ls[threadIdx.x];
  psq[blockIdx.x * 256 + threadIdx.x] = ls2[threadIdx.x];
  if (threadIdx.x < TT) pcnt[blockIdx.x * TT + threadIdx.x] = lc[threadIdx.x];
}

__global__ __launch_bounds__(256) void k_reduce_stats(const float* __restrict__ psum,
                                                      const float* __restrict__ psq,
                                                      const float* __restrict__ pcnt,
                                                      float* __restrict__ mean,
                                                      float* __restrict__ stdv,
                                                      float* __restrict__ counts) {
  __shared__ float c[TT];
  if (threadIdx.x < TT) {
    float s = 0.0f;
    for (int b = 0; b < STATS_GRID; ++b) s += pcnt[b * TT + threadIdx.x];
    counts[threadIdx.x] = s;
    c[threadIdx.x] = s;
  }
  __syncthreads();
  float s = 0.0f, q = 0.0f;
  for (int b = 0; b < STATS_GRID; ++b) {
    s += psum[b * 256 + threadIdx.x];
    q += psq[b * 256 + threadIdx.x];
  }
  float n = c[threadIdx.x >> 6];
  float m = s / n;
  mean[threadIdx.x] = m;
  stdv[threadIdx.x] = (q - s * s / n) / sqrtf(n - 1.0f);
}

// tilde = (H - mean)/std in place; LDS-private histogram -> partial dump
__global__ __launch_bounds__(256) void k_tilde_hist(float* __restrict__ H,
                                                    const int* __restrict__ nt,
                                                    const float* __restrict__ mean,
                                                    const float* __restrict__ stdv,
                                                    unsigned* __restrict__ pe, int NW) {
  __shared__ unsigned hist[BINS];
  for (int b = threadIdx.x; b < BINS; b += 256) hist[b] = 0;
  __syncthreads();
  for (int i = blockIdx.x * 256 + threadIdx.x; i < NW; i += HG * 256) {
    int nn = i >> 6, d = i & 63;
    int t = nt[nn];
    float v = (H[i] - mean[t * WH + d]) / stdv[t * WH + d];
    H[i] = v;
    int b = (int)((v + 8.0f) * BIN_SCALE);
    b = min(max(b, 0), BINS - 1);
    atomicAdd(&hist[b], 1u);
  }
  __syncthreads();
  for (int b = threadIdx.x; b < BINS; b += 256)
    pe[(size_t)blockIdx.x * BINS + b] = hist[b];
}

__global__ __launch_bounds__(256) void k_histG(const float* __restrict__ g,
                                               unsigned* __restrict__ pg, int M) {
  __shared__ unsigned hist[BINS];
  for (int b = threadIdx.x; b < BINS; b += 256) hist[b] = 0;
  __syncthreads();
  for (int i = blockIdx.x * 256 + threadIdx.x; i < M; i += HG * 256) {
    float v = g[i];
    int b = (int)((v + 8.0f) * BIN_SCALE);
    b = min(max(b, 0), BINS - 1);
    atomicAdd(&hist[b], 1u);
  }
  __syncthreads();
  for (int b = threadIdx.x; b < BINS; b += 256)
    pg[(size_t)blockIdx.x * BINS + b] = hist[b];
}

// reduce partial hists -> per-bin diff (cg - ce)
__global__ __launch_bounds__(256) void k_diff(const unsigned* __restrict__ pg,
                                              const unsigned* __restrict__ pe,
                                              int* __restrict__ diff) {
  int b = blockIdx.x * 256 + threadIdx.x;  // grid = BINS/256
  int s = 0;
  for (int p = 0; p < HG; ++p)
    s += (int)pg[(size_t)p * BINS + b] - (int)pe[(size_t)p * BINS + b];
  diff[b] = s;
}

// single block: W1 = (delta/M) * sum_b |inclusive_prefix(diff)|
__global__ __launch_bounds__(1024) void k_wass(const int* __restrict__ diff,
                                               float* __restrict__ out, int M, int NW) {
  int tid = threadIdx.x;
  int lo = tid * (BINS / 1024);
  int d[BINS / 1024];
  int s = 0;
#pragma unroll
  for (int i = 0; i < BINS / 1024; ++i) {
    d[i] = diff[lo + i];
    s += d[i];
  }
  __shared__ int sc[1024];
  sc[tid] = s;
  __syncthreads();
  for (int st = 1; st < 1024; st <<= 1) {
    int v = (tid >= st) ? sc[tid - st] : 0;
    __syncthreads();
    sc[tid] += v;
    __syncthreads();
  }
  int run = sc[tid] - s;  // exclusive prefix
  long long a = 0;
#pragma unroll
  for (int i = 0; i < BINS / 1024; ++i) {
    run += d[i];
    a += (long long)(run < 0 ? -run : run);
  }
  __shared__ long long rd[1024];
  rd[tid] = a;
  __syncthreads();
  for (int st = 512; st > 0; st >>= 1) {
    if (tid < st) rd[tid] += rd[tid + st];
    __syncthreads();
  }
  if (tid == 0) out[NW] = (float)((double)rd[0] * (1.0 / (double)BIN_SCALE) / (double)M);
}

// ---------- CSR build (counting sort of edges by dst) ----------
__global__ __launch_bounds__(256) void k_degi(const int* __restrict__ dst,
                                              unsigned* __restrict__ degi, int E) {
  int e = blockIdx.x * 256 + threadIdx.x;
  if (e < E) atomicAdd(&degi[dst[e]], 1u);
}
__global__ __launch_bounds__(256) void k_copy_u32(const unsigned* __restrict__ a,
                                                  unsigned* __restrict__ b, int n) {
  int i = blockIdx.x * 256 + threadIdx.x;
  if (i < n) b[i] = a[i];
}
__global__ __launch_bounds__(1024) void k_scan(unsigned* __restrict__ a, int L) {
  __shared__ unsigned ts[1024];
  int C = (L + 1023) / 1024;
  int lo = threadIdx.x * C, hi = min(lo + C, L);
  unsigned s = 0;
  for (int i = lo; i < hi; ++i) s += a[i];
  ts[threadIdx.x] = s;
  __syncthreads();
  for (int st = 1; st < 1024; st <<= 1) {
    unsigned v = (threadIdx.x >= (unsigned)st) ? ts[threadIdx.x - st] : 0u;
    __syncthreads();
    ts[threadIdx.x] += v;
    __syncthreads();
  }
  unsigned run = (threadIdx.x == 0) ? 0u : ts[threadIdx.x - 1];
  for (int i = lo; i < hi; ++i) {
    unsigned c = a[i];
    a[i] = run;
    run += c;
  }
}
__global__ __launch_bounds__(256) void k_build(const int* __restrict__ src,
                                               const int* __restrict__ dst,
                                               const unsigned* __restrict__ off,
                                               unsigned* __restrict__ cur,
                                               unsigned* __restrict__ esrc, int E) {
  int e = blockIdx.x * 256 + threadIdx.x;
  if (e >= E) return;
  int t = dst[e];
  unsigned p = off[t] + atomicAdd(&cur[t], 1u);
  esrc[p] = (unsigned)src[e];
}

// ---------- diffusion hop ----------
// wave per node; lane = g*8+c: 8 edge-groups (16 loads in flight), c = col eighth
__global__ __launch_bounds__(256) void k_spmm(const unsigned* __restrict__ off,
                                              const unsigned* __restrict__ degi,
                                              const unsigned* __restrict__ esrc,
                                              const float* __restrict__ Z,
                                              const float* __restrict__ tilde,
                                              float* __restrict__ Zn, int N) {
  int wv = threadIdx.x >> 6, lane = threadIdx.x & 63;
  int n = blockIdx.x * 4 + wv;
  if (n >= N) return;
  int g = lane >> 3, c = lane & 7;
  unsigned st = off[n], dg = degi[n];
  float4 a0 = {0.f, 0.f, 0.f, 0.f}, a1 = {0.f, 0.f, 0.f, 0.f};
  for (unsigned e = g; e < dg; e += 8) {
    unsigned s = esrc[st + e];
    const float4* Zr = (const float4*)(Z + (size_t)s * WH);
    float4 v0 = Zr[c];
    float4 v1 = Zr[c + 8];
    a0.x += v0.x; a0.y += v0.y; a0.z += v0.z; a0.w += v0.w;
    a1.x += v1.x; a1.y += v1.y; a1.z += v1.z; a1.w += v1.w;
  }
#pragma unroll
  for (int m = 8; m <= 32; m <<= 1) {
    a0.x += __shfl_xor(a0.x, m, 64);
    a0.y += __shfl_xor(a0.y, m, 64);
    a0.z += __shfl_xor(a0.z, m, 64);
    a0.w += __shfl_xor(a0.w, m, 64);
    a1.x += __shfl_xor(a1.x, m, 64);
    a1.y += __shfl_xor(a1.y, m, 64);
    a1.z += __shfl_xor(a1.z, m, 64);
    a1.w += __shfl_xor(a1.w, m, 64);
  }
  if (g == 0) {
    float wn = (1.0f - ALPHA_C) / fmaxf((float)dg, 1.0f);
    const float4* Tr = (const float4*)(tilde + (size_t)n * WH);
    float4 t0 = Tr[c], t1 = Tr[c + 8];
    float4 o0 = {wn * a0.x + ALPHA_C * t0.x, wn * a0.y + ALPHA_C * t0.y,
                 wn * a0.z + ALPHA_C * t0.z, wn * a0.w + ALPHA_C * t0.w};
    float4 o1 = {wn * a1.x + ALPHA_C * t1.x, wn * a1.y + ALPHA_C * t1.y,
                 wn * a1.z + ALPHA_C * t1.z, wn * a1.w + ALPHA_C * t1.w};
    float4* Or = (float4*)(Zn + (size_t)n * WH);
    Or[c] = o0;
    Or[c + 8] = o1;
  }
}

// ---------- epilogue: denorm + row-L2 ----------
__global__ __launch_bounds__(256) void k_final(const float* __restrict__ Z,
                                               const int* __restrict__ nt,
                                               const float* __restrict__ mean,
                                               const float* __restrict__ stdv,
                                               float* __restrict__ out, int N) {
  int wv = threadIdx.x >> 6, lane = threadIdx.x & 63;
  int n = blockIdx.x * 4 + wv;
  if (n >= N) return;
  int t = nt[n];
  float z = Z[(size_t)n * WH + lane] * stdv[t * WH + lane] + mean[t * WH + lane];
  float s = z * z;
#pragma unroll
  for (int off = 32; off > 0; off >>= 1) s += __shfl_xor(s, off, 64);
  float r = 1.0f / fmaxf(sqrtf(s), 1e-12f);
  out[(size_t)n * WH + lane] = z * r;
}

extern "C" void kernel_launch(void* const* d_in, const int* in_sizes, int n_in,
                              void* d_out, int out_size, void* d_ws, size_t ws_size,
                              hipStream_t stream) {
  const float* X = (const float*)d_in[0];
  const float* W = (const float*)d_in[1];
  const float* bias = (const float*)d_in[2];
  const float* g = (const float*)d_in[3];
  const int* ei = (const int*)d_in[4];
  const int* nt = (const int*)d_in[5];

  const int N = in_sizes[5];
  const int E = in_sizes[4] / 2;
  const int M = in_sizes[3];  // N * WH
  const int NW = N * WH;
  const int* srcp = ei;
  const int* dstp = ei + E;

  char* w = (char*)d_ws;
  size_t o = 0;
  auto alloc = [&](size_t bytes) {
    size_t r = o;
    o += (bytes + 255) & ~(size_t)255;
    return r;
  };
  size_t off_stats = alloc(4096);  // counts@0, mean@256, std@1280
  size_t off_psum  = alloc((size_t)STATS_GRID * 256 * 4);
  size_t off_psq   = alloc((size_t)STATS_GRID * 256 * 4);
  size_t off_pcnt  = alloc((size_t)STATS_GRID * TT * 4);
  size_t off_diff  = alloc((size_t)BINS * 4);
  size_t off_degi  = alloc((size_t)N * 4);  // memset region start
  size_t off_cur   = alloc((size_t)N * 4);  // memset region end (256B-aligned slot!)
  size_t off_off   = alloc((size_t)N * 4);
  size_t off_esrc  = alloc((size_t)E * 4);
  size_t off_tilde = alloc((size_t)NW * 4);
  size_t off_bufA  = alloc((size_t)NW * 4);  // partial hists alias here (16 MB < 25.6 MB)
  size_t off_bufB  = alloc((size_t)NW * 4);

  float* counts = (float*)(w + off_stats + 0);
  float* mean   = (float*)(w + off_stats + 256);
  float* stdv   = (float*)(w + off_stats + 1280);
  float* psum   = (float*)(w + off_psum);
  float* psq    = (float*)(w + off_psq);
  float* pcnt   = (float*)(w + off_pcnt);
  int* diff     = (int*)(w + off_diff);
  unsigned* degi = (unsigned*)(w + off_degi);
  unsigned* cur  = (unsigned*)(w + off_cur);
  unsigned* offp = (unsigned*)(w + off_off);
  unsigned* esrc = (unsigned*)(w + off_esrc);
  float* tilde   = (float*)(w + off_tilde);
  float* bufA    = (float*)(w + off_bufA);
  float* bufB    = (float*)(w + off_bufB);
  // partial hist arrays (HG*BINS*4 = 16 MB each) alias the idle ping-pong buffers
  unsigned* pg = (unsigned*)(w + off_bufA);
  unsigned* pe = (unsigned*)(w + off_bufB);
  float* out = (float*)d_out;

  // zero degree+cursor. Span covers the alignment pad between slots (round-2 bug).
  hipMemsetAsync(w + off_degi, 0, off_cur - off_degi + (size_t)N * 4, stream);

  // 1) encode + L2 norm -> tilde buffer (holds H for now)
  k_encode<<<(N + BN - 1) / BN, 256, 0, stream>>>(X, W, bias, tilde, N);

  // 2) per-type stats (fused sum/sumsq/count) + reduce
  k_stats<<<STATS_GRID, 256, 0, stream>>>(tilde, nt, psum, psq, pcnt, NW);
  k_reduce_stats<<<1, 256, 0, stream>>>(psum, psq, pcnt, mean, stdv, counts);

  // 3) tilde in place + LDS histograms (partials fully overwritten -> no memset)
  k_tilde_hist<<<HG, 256, 0, stream>>>(tilde, nt, mean, stdv, pe, NW);
  k_histG<<<HG, 256, 0, stream>>>(g, pg, M);

  // 4) W1 = (delta/M) * sum_b |prefix(cg-ce)|
  k_diff<<<BINS / 256, 256, 0, stream>>>(pg, pe, diff);
  k_wass<<<1, 1024, 0, stream>>>(diff, out, M, NW);

  // 5) CSR build (edges grouped by dst)
  k_degi<<<(E + 255) / 256, 256, 0, stream>>>(dstp, degi, E);
  k_copy_u32<<<(N + 255) / 256, 256, 0, stream>>>(degi, offp, N);
  k_scan<<<1, 1024, 0, stream>>>(offp, N);
  k_build<<<(E + 255) / 256, 256, 0, stream>>>(srcp, dstp, offp, cur, esrc, E);

  // 6) K=10 diffusion hops, ping-pong (partial hists dead now)
  const float* Zc = tilde;
  for (int k = 0; k < 10; ++k) {
    float* Zn = (k & 1) ? bufB : bufA;
    k_spmm<<<(N + 3) / 4, 256, 0, stream>>>(offp, degi, esrc, Zc, tilde, Zn, N);
    Zc = Zn;
  }

  // 7) denorm + row L2 -> out
  k_final<<<(N + 3) / 4, 256, 0, stream>>>(Zc, nt, mean, stdv, out, N);
}

// Round 5
// 1253.854 us; speedup vs baseline: 2.2765x; 1.1432x over previous
//
#include <hip/hip_runtime.h>
#include <math.h>

#define WH 64
#define WIN 256
#define TT 4
#define ALPHA_C 0.1f
#define STATS_GRID 256
#define BN 64
#define KC 32
#define XS_STRIDE (KC + 4)
#define BINS 16384              // bins over [-8, 8)
#define BIN_SCALE 1024.0f       // BINS / 16
#define HG 256                  // histogram grid (partial hists)

typedef unsigned short ushortT;

__device__ __forceinline__ unsigned pack_bf16(float a, float b) {
  unsigned ua = __float_as_uint(a), ub = __float_as_uint(b);
  ua = (ua + 0x7FFFu + ((ua >> 16) & 1u)) >> 16;          // RNE
  ub = ((ub + 0x7FFFu + ((ub >> 16) & 1u)) >> 16) << 16;
  return (ua & 0xFFFFu) | ub;
}
__device__ __forceinline__ float bf_lo(unsigned p) { return __uint_as_float(p << 16); }
__device__ __forceinline__ float bf_hi(unsigned p) { return __uint_as_float(p & 0xFFFF0000u); }

// ---------- encode: H = l2norm_rows(X @ W + b), tiled fp32, KC=32 ----------
__global__ __launch_bounds__(256) void k_encode(const float* __restrict__ X,
                                                const float* __restrict__ W,
                                                const float* __restrict__ bias,
                                                float* __restrict__ H, int N) {
  __shared__ __align__(16) float Xs[BN * XS_STRIDE];
  __shared__ __align__(16) float Ws[KC * WH];
  int tid = threadIdx.x;
  int tn = tid >> 4, tc = tid & 15;
  int nodeBase = blockIdx.x * BN;
  float acc[4][4] = {};
  for (int k0 = 0; k0 < WIN; k0 += KC) {
    __syncthreads();
    // stage W chunk: KC*WH = 2048 floats = 512 float4
    const float4* Wg4 = (const float4*)(W + (size_t)k0 * WH);
    float4* Ws4 = (float4*)Ws;
    Ws4[tid] = Wg4[tid];
    Ws4[tid + 256] = Wg4[tid + 256];
    // stage X chunk: 64 nodes x 32 k = 512 float4; idx -> node = idx>>3, f4 = idx&7
#pragma unroll
    for (int i = 0; i < 2; ++i) {
      int idx = tid + i * 256;
      int ln = idx >> 3, f4 = idx & 7;
      int node = nodeBase + ln;
      if (node < N) {
        *(float4*)&Xs[ln * XS_STRIDE + f4 * 4] =
            *(const float4*)(X + (size_t)node * WIN + k0 + f4 * 4);
      }
    }
    __syncthreads();
    for (int kk = 0; kk < KC; kk += 4) {
      float4 b0 = *(const float4*)&Ws[(kk + 0) * WH + tc * 4];
      float4 b1 = *(const float4*)&Ws[(kk + 1) * WH + tc * 4];
      float4 b2 = *(const float4*)&Ws[(kk + 2) * WH + tc * 4];
      float4 b3 = *(const float4*)&Ws[(kk + 3) * WH + tc * 4];
#pragma unroll
      for (int i = 0; i < 4; ++i) {
        float4 a = *(const float4*)&Xs[(tn * 4 + i) * XS_STRIDE + kk];
        acc[i][0] += a.x * b0.x + a.y * b1.x + a.z * b2.x + a.w * b3.x;
        acc[i][1] += a.x * b0.y + a.y * b1.y + a.z * b2.y + a.w * b3.y;
        acc[i][2] += a.x * b0.z + a.y * b1.z + a.z * b2.z + a.w * b3.z;
        acc[i][3] += a.x * b0.w + a.y * b1.w + a.z * b2.w + a.w * b3.w;
      }
    }
  }
  float4 bv = *(const float4*)(bias + tc * 4);
#pragma unroll
  for (int i = 0; i < 4; ++i) {
    float h0 = acc[i][0] + bv.x, h1 = acc[i][1] + bv.y;
    float h2 = acc[i][2] + bv.z, h3 = acc[i][3] + bv.w;
    float s = h0 * h0 + h1 * h1 + h2 * h2 + h3 * h3;
    s += __shfl_xor(s, 1, 64);
    s += __shfl_xor(s, 2, 64);
    s += __shfl_xor(s, 4, 64);
    s += __shfl_xor(s, 8, 64);
    float r = 1.0f / fmaxf(sqrtf(s), 1e-12f);
    int node = nodeBase + tn * 4 + i;
    if (node < N) {
      float4 o = {h0 * r, h1 * r, h2 * r, h3 * r};
      *(float4*)(H + (size_t)node * WH + tc * 4) = o;
    }
  }
}

// ---------- per-type stats: fused sum + sumsq + counts ----------
__global__ __launch_bounds__(256) void k_stats(const float* __restrict__ H,
                                               const int* __restrict__ nt,
                                               float* __restrict__ psum,
                                               float* __restrict__ psq,
                                               float* __restrict__ pcnt, int NW) {
  __shared__ float ls[TT * WH], ls2[TT * WH];
  __shared__ float lc[TT];
  ls[threadIdx.x] = 0.0f;
  ls2[threadIdx.x] = 0.0f;
  if (threadIdx.x < TT) lc[threadIdx.x] = 0.0f;
  __syncthreads();
  for (int i = blockIdx.x * 256 + threadIdx.x; i < NW; i += STATS_GRID * 256) {
    int nn = i >> 6, d = i & 63;
    int t = nt[nn];
    float v = H[i];
    atomicAdd(&ls[t * WH + d], v);
    atomicAdd(&ls2[t * WH + d], v * v);
    if (d == 0) atomicAdd(&lc[t], 1.0f);
  }
  __syncthreads();
  psum[blockIdx.x * 256 + threadIdx.x] = ls[threadIdx.x];
  psq[blockIdx.x * 256 + threadIdx.x] = ls2[threadIdx.x];
  if (threadIdx.x < TT) pcnt[blockIdx.x * TT + threadIdx.x] = lc[threadIdx.x];
}

__global__ __launch_bounds__(256) void k_reduce_stats(const float* __restrict__ psum,
                                                      const float* __restrict__ psq,
                                                      const float* __restrict__ pcnt,
                                                      float* __restrict__ mean,
                                                      float* __restrict__ stdv,
                                                      float* __restrict__ counts) {
  __shared__ float c[TT];
  if (threadIdx.x < TT) {
    float s = 0.0f;
    for (int b = 0; b < STATS_GRID; ++b) s += pcnt[b * TT + threadIdx.x];
    counts[threadIdx.x] = s;
    c[threadIdx.x] = s;
  }
  __syncthreads();
  float s = 0.0f, q = 0.0f;
  for (int b = 0; b < STATS_GRID; ++b) {
    s += psum[b * 256 + threadIdx.x];
    q += psq[b * 256 + threadIdx.x];
  }
  float n = c[threadIdx.x >> 6];
  float m = s / n;
  mean[threadIdx.x] = m;
  stdv[threadIdx.x] = (q - s * s / n) / sqrtf(n - 1.0f);
}

// tilde = (H - mean)/std in place + bf16 copy; LDS-private histogram -> partial dump
__global__ __launch_bounds__(256) void k_tilde_hist(float* __restrict__ H,
                                                    const int* __restrict__ nt,
                                                    const float* __restrict__ mean,
                                                    const float* __restrict__ stdv,
                                                    ushortT* __restrict__ tb,
                                                    unsigned* __restrict__ pe, int NW) {
  __shared__ unsigned hist[BINS];
  for (int b = threadIdx.x; b < BINS; b += 256) hist[b] = 0;
  __syncthreads();
  for (int i = blockIdx.x * 256 + threadIdx.x; i < NW; i += HG * 256) {
    int nn = i >> 6, d = i & 63;
    int t = nt[nn];
    float v = (H[i] - mean[t * WH + d]) / stdv[t * WH + d];
    H[i] = v;
    unsigned u = __float_as_uint(v);
    tb[i] = (ushortT)((u + 0x7FFFu + ((u >> 16) & 1u)) >> 16);
    int b = (int)((v + 8.0f) * BIN_SCALE);
    b = min(max(b, 0), BINS - 1);
    atomicAdd(&hist[b], 1u);
  }
  __syncthreads();
  for (int b = threadIdx.x; b < BINS; b += 256)
    pe[(size_t)blockIdx.x * BINS + b] = hist[b];
}

__global__ __launch_bounds__(256) void k_histG(const float* __restrict__ g,
                                               unsigned* __restrict__ pg, int M) {
  __shared__ unsigned hist[BINS];
  for (int b = threadIdx.x; b < BINS; b += 256) hist[b] = 0;
  __syncthreads();
  for (int i = blockIdx.x * 256 + threadIdx.x; i < M; i += HG * 256) {
    float v = g[i];
    int b = (int)((v + 8.0f) * BIN_SCALE);
    b = min(max(b, 0), BINS - 1);
    atomicAdd(&hist[b], 1u);
  }
  __syncthreads();
  for (int b = threadIdx.x; b < BINS; b += 256)
    pg[(size_t)blockIdx.x * BINS + b] = hist[b];
}

__global__ __launch_bounds__(256) void k_diff(const unsigned* __restrict__ pg,
                                              const unsigned* __restrict__ pe,
                                              int* __restrict__ diff) {
  int b = blockIdx.x * 256 + threadIdx.x;
  int s = 0;
  for (int p = 0; p < HG; ++p)
    s += (int)pg[(size_t)p * BINS + b] - (int)pe[(size_t)p * BINS + b];
  diff[b] = s;
}

__global__ __launch_bounds__(1024) void k_wass(const int* __restrict__ diff,
                                               float* __restrict__ out, int M, int NW) {
  int tid = threadIdx.x;
  int lo = tid * (BINS / 1024);
  int d[BINS / 1024];
  int s = 0;
#pragma unroll
  for (int i = 0; i < BINS / 1024; ++i) {
    d[i] = diff[lo + i];
    s += d[i];
  }
  __shared__ int sc[1024];
  sc[tid] = s;
  __syncthreads();
  for (int st = 1; st < 1024; st <<= 1) {
    int v = (tid >= st) ? sc[tid - st] : 0;
    __syncthreads();
    sc[tid] += v;
    __syncthreads();
  }
  int run = sc[tid] - s;
  long long a = 0;
#pragma unroll
  for (int i = 0; i < BINS / 1024; ++i) {
    run += d[i];
    a += (long long)(run < 0 ? -run : run);
  }
  __shared__ long long rd[1024];
  rd[tid] = a;
  __syncthreads();
  for (int st = 512; st > 0; st >>= 1) {
    if (tid < st) rd[tid] += rd[tid + st];
    __syncthreads();
  }
  if (tid == 0) out[NW] = (float)((double)rd[0] * (1.0 / (double)BIN_SCALE) / (double)M);
}

// ---------- CSR build ----------
__global__ __launch_bounds__(256) void k_degi(const int* __restrict__ dst,
                                              unsigned* __restrict__ degi, int E) {
  int e = blockIdx.x * 256 + threadIdx.x;
  if (e < E) atomicAdd(&degi[dst[e]], 1u);
}
// exclusive scan: out = exscan(in), one 1024-thread block
__global__ __launch_bounds__(1024) void k_scan(const unsigned* __restrict__ in,
                                               unsigned* __restrict__ outp, int L) {
  __shared__ unsigned ts[1024];
  int C = (L + 1023) / 1024;
  int lo = threadIdx.x * C, hi = min(lo + C, L);
  unsigned s = 0;
  for (int i = lo; i < hi; ++i) s += in[i];
  ts[threadIdx.x] = s;
  __syncthreads();
  for (int st = 1; st < 1024; st <<= 1) {
    unsigned v = (threadIdx.x >= (unsigned)st) ? ts[threadIdx.x - st] : 0u;
    __syncthreads();
    ts[threadIdx.x] += v;
    __syncthreads();
  }
  unsigned run = (threadIdx.x == 0) ? 0u : ts[threadIdx.x - 1];
  for (int i = lo; i < hi; ++i) {
    unsigned c = in[i];
    outp[i] = run;
    run += c;
  }
}
__global__ __launch_bounds__(256) void k_build(const int* __restrict__ src,
                                               const int* __restrict__ dst,
                                               const unsigned* __restrict__ off,
                                               unsigned* __restrict__ cur,
                                               unsigned* __restrict__ esrc, int E) {
  int e = blockIdx.x * 256 + threadIdx.x;
  if (e >= E) return;
  int t = dst[e];
  unsigned p = off[t] + atomicAdd(&cur[t], 1u);
  esrc[p] = (unsigned)src[e];
}

// ---------- diffusion hop (bf16 Z) ----------
// wave per node; lane = g*8+c: 8 edge-groups, c = col-eighth (8 bf16 = 16 B per lane)
__global__ __launch_bounds__(256) void k_spmm(const unsigned* __restrict__ off,
                                              const unsigned* __restrict__ degi,
                                              const unsigned* __restrict__ esrc,
                                              const ushortT* __restrict__ Zb,
                                              const float* __restrict__ tilde,
                                              ushortT* __restrict__ Zn, int N) {
  int wv = threadIdx.x >> 6, lane = threadIdx.x & 63;
  int n = blockIdx.x * 4 + wv;
  if (n >= N) return;
  int g = lane >> 3, c = lane & 7;
  unsigned st = off[n], dg = degi[n];
  float a[8] = {};
  for (unsigned e = g; e < dg; e += 8) {
    unsigned s = esrc[st + e];
    uint4 v = *((const uint4*)(Zb + (size_t)s * WH) + c);
    a[0] += bf_lo(v.x); a[1] += bf_hi(v.x);
    a[2] += bf_lo(v.y); a[3] += bf_hi(v.y);
    a[4] += bf_lo(v.z); a[5] += bf_hi(v.z);
    a[6] += bf_lo(v.w); a[7] += bf_hi(v.w);
  }
#pragma unroll
  for (int m = 8; m <= 32; m <<= 1) {
#pragma unroll
    for (int j = 0; j < 8; ++j) a[j] += __shfl_xor(a[j], m, 64);
  }
  if (g == 0) {
    float wn = (1.0f - ALPHA_C) / fmaxf((float)dg, 1.0f);
    const float4* Tr = (const float4*)(tilde + (size_t)n * WH);
    float4 t0 = Tr[2 * c], t1 = Tr[2 * c + 1];
    float o0 = wn * a[0] + ALPHA_C * t0.x, o1 = wn * a[1] + ALPHA_C * t0.y;
    float o2 = wn * a[2] + ALPHA_C * t0.z, o3 = wn * a[3] + ALPHA_C * t0.w;
    float o4 = wn * a[4] + ALPHA_C * t1.x, o5 = wn * a[5] + ALPHA_C * t1.y;
    float o6 = wn * a[6] + ALPHA_C * t1.z, o7 = wn * a[7] + ALPHA_C * t1.w;
    uint4 p;
    p.x = pack_bf16(o0, o1);
    p.y = pack_bf16(o2, o3);
    p.z = pack_bf16(o4, o5);
    p.w = pack_bf16(o6, o7);
    *((uint4*)(Zn + (size_t)n * WH) + c) = p;
  }
}

// ---------- epilogue: denorm + row-L2 (bf16 Z in) ----------
__global__ __launch_bounds__(256) void k_final(const ushortT* __restrict__ Zb,
                                               const int* __restrict__ nt,
                                               const float* __restrict__ mean,
                                               const float* __restrict__ stdv,
                                               float* __restrict__ out, int N) {
  int wv = threadIdx.x >> 6, lane = threadIdx.x & 63;
  int n = blockIdx.x * 4 + wv;
  if (n >= N) return;
  int t = nt[n];
  float zv = __uint_as_float((unsigned)Zb[(size_t)n * WH + lane] << 16);
  float z = zv * stdv[t * WH + lane] + mean[t * WH + lane];
  float s = z * z;
#pragma unroll
  for (int off = 32; off > 0; off >>= 1) s += __shfl_xor(s, off, 64);
  float r = 1.0f / fmaxf(sqrtf(s), 1e-12f);
  out[(size_t)n * WH + lane] = z * r;
}

extern "C" void kernel_launch(void* const* d_in, const int* in_sizes, int n_in,
                              void* d_out, int out_size, void* d_ws, size_t ws_size,
                              hipStream_t stream) {
  const float* X = (const float*)d_in[0];
  const float* W = (const float*)d_in[1];
  const float* bias = (const float*)d_in[2];
  const float* g = (const float*)d_in[3];
  const int* ei = (const int*)d_in[4];
  const int* nt = (const int*)d_in[5];

  const int N = in_sizes[5];
  const int E = in_sizes[4] / 2;
  const int M = in_sizes[3];  // N * WH
  const int NW = N * WH;
  const int* srcp = ei;
  const int* dstp = ei + E;

  char* w = (char*)d_ws;
  size_t o = 0;
  auto alloc = [&](size_t bytes) {
    size_t r = o;
    o += (bytes + 255) & ~(size_t)255;
    return r;
  };
  size_t off_stats = alloc(4096);  // counts@0, mean@256, std@1280
  size_t off_psum  = alloc((size_t)STATS_GRID * 256 * 4);
  size_t off_psq   = alloc((size_t)STATS_GRID * 256 * 4);
  size_t off_pcnt  = alloc((size_t)STATS_GRID * TT * 4);
  size_t off_diff  = alloc((size_t)BINS * 4);
  size_t off_degi  = alloc((size_t)N * 4);  // memset region start
  size_t off_cur   = alloc((size_t)N * 4);  // memset region end (256B-aligned slot!)
  size_t off_off   = alloc((size_t)N * 4);
  size_t off_esrc  = alloc((size_t)E * 4);
  size_t off_tilde = alloc((size_t)NW * 4);
  size_t off_tbf   = alloc((size_t)NW * 2);  // bf16 tilde (hop-0 gather source)
  size_t off_bufA  = alloc((size_t)NW * 4);  // partial hists alias; later bf16 Z ping
  size_t off_bufB  = alloc((size_t)NW * 4);  // partial hists alias; later bf16 Z pong

  float* counts = (float*)(w + off_stats + 0);
  float* mean   = (float*)(w + off_stats + 256);
  float* stdv   = (float*)(w + off_stats + 1280);
  float* psum   = (float*)(w + off_psum);
  float* psq    = (float*)(w + off_psq);
  float* pcnt   = (float*)(w + off_pcnt);
  int* diff     = (int*)(w + off_diff);
  unsigned* degi = (unsigned*)(w + off_degi);
  unsigned* cur  = (unsigned*)(w + off_cur);
  unsigned* offp = (unsigned*)(w + off_off);
  unsigned* esrc = (unsigned*)(w + off_esrc);
  float* tilde   = (float*)(w + off_tilde);
  ushortT* tbf   = (ushortT*)(w + off_tbf);
  unsigned* pg   = (unsigned*)(w + off_bufA);
  unsigned* pe   = (unsigned*)(w + off_bufB);
  ushortT* ZA    = (ushortT*)(w + off_bufA);
  ushortT* ZB    = (ushortT*)(w + off_bufB);
  float* out = (float*)d_out;

  // zero degree+cursor; span covers the alignment pad between slots.
  hipMemsetAsync(w + off_degi, 0, off_cur - off_degi + (size_t)N * 4, stream);

  // 1) encode + L2 norm -> tilde buffer (holds H for now)
  k_encode<<<(N + BN - 1) / BN, 256, 0, stream>>>(X, W, bias, tilde, N);

  // 2) per-type stats (fused sum/sumsq/count) + reduce
  k_stats<<<STATS_GRID, 256, 0, stream>>>(tilde, nt, psum, psq, pcnt, NW);
  k_reduce_stats<<<1, 256, 0, stream>>>(psum, psq, pcnt, mean, stdv, counts);

  // 3) tilde in place (+bf16 copy) + LDS histograms
  k_tilde_hist<<<HG, 256, 0, stream>>>(tilde, nt, mean, stdv, tbf, pe, NW);
  k_histG<<<HG, 256, 0, stream>>>(g, pg, M);

  // 4) W1 = (delta/M) * sum_b |prefix(cg-ce)|
  k_diff<<<BINS / 256, 256, 0, stream>>>(pg, pe, diff);
  k_wass<<<1, 1024, 0, stream>>>(diff, out, M, NW);

  // 5) CSR build
  k_degi<<<(E + 255) / 256, 256, 0, stream>>>(dstp, degi, E);
  k_scan<<<1, 1024, 0, stream>>>(degi, offp, N);
  k_build<<<(E + 255) / 256, 256, 0, stream>>>(srcp, dstp, offp, cur, esrc, E);

  // 6) K=10 diffusion hops, bf16 ping-pong (partial hists dead now)
  const ushortT* Zc = tbf;
  for (int k = 0; k < 10; ++k) {
    ushortT* Zn = (k & 1) ? ZB : ZA;
    k_spmm<<<(N + 3) / 4, 256, 0, stream>>>(offp, degi, esrc, Zc, tilde, Zn, N);
    Zc = Zn;
  }

  // 7) denorm + row L2 -> out
  k_final<<<(N + 3) / 4, 256, 0, stream>>>(Zc, nt, mean, stdv, out, N);
}